// Round 4
// baseline (72.053 us; speedup 1.0000x reference)
//
#include <hip/hip_runtime.h>

#define DEV __device__ __forceinline__

// descending compare-exchange
DEV void ce_desc(float &a, float &b) {
    float hi = fmaxf(a, b);
    float lo = fminf(a, b);
    a = hi;
    b = lo;
}

// Batcher odd-even mergesort generated for n=32, pruned to 27 wires
// (valid: virtual pads = -inf at wires 27..31 never move, so every
// comparator touching wire >= 27 is a no-op). Descending, fully
// unrolled -> all indices compile-time constants -> stays in VGPRs.
// Operates on TWO independent arrays in lockstep: every layer already
// has ~13 independent comparators per array, and pairing the arrays
// doubles the independent stream count on the serial critical path.
DEV void sort27x2_desc(float (&a)[27], float (&b)[27]) {
#pragma unroll
    for (int p = 1; p < 32; p <<= 1) {
#pragma unroll
        for (int k = p; k >= 1; k >>= 1) {
#pragma unroll
            for (int j = k % p; j + k < 32; j += 2 * k) {
#pragma unroll
                for (int i = 0; i < k; ++i) {
                    if ((i + j + k) < 27 &&
                        (i + j) / (2 * p) == (i + j + k) / (2 * p)) {
                        ce_desc(a[i + j], a[i + j + k]);
                        ce_desc(b[i + j], b[i + j + k]);
                    }
                }
            }
        }
    }
}

// s[0..26] = w sorted descending (the 54 z-values are 3.5 +- w).
// spike = 3.5 + min over m=1..54 of (g - Q)/m with
//   Q = Q_m (sum of m largest w)  for m <= 27,
//   Q = Q_{54-m}                  for m > 27.
// D tracks g - Q_i directly; nested fminf is v_min3_f32-fusable.
DEV float spike_from_sorted(const float (&s)[27], float g) {
    float D = g;
    float best = D * (1.0f / 54.0f);  // m = 54 (Q_0 = 0)
#pragma unroll
    for (int i = 1; i <= 26; ++i) {
        D -= s[i - 1];
        const float c0 = D * (1.0f / (float)i);         // m = i
        const float c1 = D * (1.0f / (float)(54 - i));  // m = 54 - i
        best = fminf(fminf(best, c0), c1);              // -> v_min3_f32
    }
    D -= s[26];
    best = fminf(best, D * (1.0f / 27.0f));             // m = 27
    return 3.5f + best;
}

__global__ __launch_bounds__(256) void spikeconv_kernel(
        const float* __restrict__ X,      // [8,32,32,3]
        const float* __restrict__ K,      // [27,64]
        const int* __restrict__ gamma_p,  // scalar
        float* __restrict__ O) {          // [8,32,32,64]
    const int f = threadIdx.x & 63;
    const int pid = blockIdx.x * 4 + (threadIdx.x >> 6);  // [0, 8192)
    const int b = pid >> 10;
    const int hw = pid & 1023;
    const int h = hw >> 5;
    const int w = hw & 31;
    const float g = (float)(*gamma_p);

    float sp[27];  // |p + 0.5k|
    float sm[27];  // |p - 0.5k|

#pragma unroll
    for (int di = 0; di < 3; ++di) {
#pragma unroll
        for (int dj = 0; dj < 3; ++dj) {
            const int y = h + di - 1;
            const int x = w + dj - 1;
            const bool inb = ((unsigned)y < 32u) && ((unsigned)x < 32u);
            const float* src = X + (((b * 32 + y) * 32 + x) * 3);
#pragma unroll
            for (int c = 0; c < 3; ++c) {
                const int d = (di * 3 + dj) * 3 + c;
                const float pv = inb ? src[c] : 0.0f;   // wave-uniform branch
                const float kv = K[d * 64 + f];         // coalesced over f
                sp[d] = fabsf(fmaf(0.5f, kv, pv));
                sm[d] = fabsf(fmaf(-0.5f, kv, pv));
            }
        }
    }

    // fused dual sort: two independent CE streams per network layer
    sort27x2_desc(sp, sm);

    const float tp = spike_from_sorted(sp, g);
    const float tm = spike_from_sorted(sm, g);

    O[pid * 64 + f] = fmaxf(tp - tm, 0.0f);  // relu, coalesced store
}

extern "C" void kernel_launch(void* const* d_in, const int* in_sizes, int n_in,
                              void* d_out, int out_size, void* d_ws, size_t ws_size,
                              hipStream_t stream) {
    const float* X = (const float*)d_in[0];        // 8*32*32*3
    const float* K = (const float*)d_in[1];        // 27*64
    const int* gamma_p = (const int*)d_in[2];      // scalar int
    float* O = (float*)d_out;                      // 8*32*32*64

    // 8192 patches * 64 filters = 524288 threads; 4 patches per 256-thread block.
    dim3 grid(2048), block(256);
    hipLaunchKernelGGL(spikeconv_kernel, grid, block, 0, stream, X, K, gamma_p, O);
}